// Round 9
// baseline (152.466 us; speedup 1.0000x reference)
//
#include <hip/hip_runtime.h>
#include <cstdint>
#include <cstddef>

typedef unsigned long long u64;

// ---------------- problem constants ----------------
constexpr int Bn   = 8;
constexpr int Pn   = 2000;
constexpr int Cn   = 81;
constexpr int CM1  = 80;
constexpr int KPRE = 2048;
constexpr int NDET = 100;
constexpr int SECP = 8;              // proposals per K1 block
constexpr int NSEC2 = Pn / SECP;     // 250 sections per image
constexpr int SSLOT = 160;           // slice stride (hard max 8*19 = 152)
constexpr int CAP  = 4096;           // post-threshold cap (held since round 4)
constexpr int NBINS = 5632;          // score-bits histogram bins
constexpr int BINOFF = (122 << 10);  // exponent 122 (scores > 0.05 > 2^-5)
constexpr float W_IMG = 1333.0f;
constexpr float H_IMG = 800.0f;
constexpr float XFORM_CLIP = 4.135166556742356f; // log(1000/16)
constexpr float NMS_OFF = 1334.0f;               // max(W,H)+1

// ---------------- ws layout (bytes); everything written before read ----------
constexpr size_t OFF_SL   = 0;                                    // Bn*NSEC2*SSLOT u64
constexpr size_t OFF_SC   = OFF_SL + (size_t)Bn * NSEC2 * SSLOT * 8; // Bn*NSEC2 int
constexpr size_t OFF_CANDA = OFF_SC + (size_t)Bn * NSEC2 * 4;     // Bn*CAP u64

__device__ __forceinline__ void decode_clip(const float4 rv, float w, float h,
                                            float cx, float cy, float out[4]) {
  float dx = rv.x / 10.0f;
  float dy = rv.y / 10.0f;
  float dw = fminf(rv.z / 5.0f, XFORM_CLIP);
  float dh = fminf(rv.w / 5.0f, XFORM_CLIP);
  float pcx = dx * w + cx;
  float pcy = dy * h + cy;
  float pw = expf(dw) * w;
  float ph = expf(dh) * h;
  out[0] = fminf(fmaxf(pcx - 0.5f * pw, 0.0f), W_IMG);
  out[1] = fminf(fmaxf(pcy - 0.5f * ph, 0.0f), H_IMG);
  out[2] = fminf(fmaxf(pcx + 0.5f * pw, 0.0f), W_IMG);
  out[3] = fminf(fmaxf(pcy + 0.5f * ph, 0.0f), H_IMG);
}

__device__ __forceinline__ int score_bin(unsigned bits) {
  int bin = (int)(bits >> 13) - BINOFF;
  return min(max(bin, 0), NBINS - 1);
}

// decode a candidate key into raw clipped box + label + score
__device__ __forceinline__ void key_decode(u64 key, int b,
                                           const float* __restrict__ reg,
                                           const float* __restrict__ props,
                                           float bx[4], int& label, float& sc) {
  sc = __uint_as_float((unsigned)(key >> 32));
  bx[0] = bx[1] = bx[2] = bx[3] = 0.0f;
  label = 0;
  if (key != 0ull) {
    int m = (int)(0xFFFFFFFFu - (unsigned)key);
    int p = m / CM1;
    int c = m - p * CM1 + 1;
    int nidx = b * Pn + p;
    const float4 pb = *reinterpret_cast<const float4*>(props + (size_t)nidx * 4);
    float w = pb.z - pb.x, h = pb.w - pb.y;
    float cx = pb.x + 0.5f * w, cy = pb.y + 0.5f * h;
    float4 rv = *reinterpret_cast<const float4*>(reg + (size_t)nidx * (Cn * 4) + c * 4);
    decode_clip(rv, w, h, cx, cy, bx);
    label = c;
  }
}

// ---------------- K1: softmax + decode + valid -> key slices ----------------
__global__ __launch_bounds__(256) void
k1_score(const float* __restrict__ logits, const float* __restrict__ reg,
         const float* __restrict__ props, u64* __restrict__ slices,
         int* __restrict__ scnt) {
  int blk = blockIdx.x, t = threadIdx.x, lane = t & 63, wv = t >> 6;
  int b = blk / NSEC2, sec = blk % NSEC2;
  __shared__ u64 cbuf[SSLOT];
  __shared__ int cnt_sh;
  if (t == 0) cnt_sh = 0;
  __syncthreads();

  #pragma unroll
  for (int pp = wv; pp < SECP; pp += 4) {
    int p = sec * SECP + pp;
    int wid = b * Pn + p;
    const float* lg = logits + (size_t)wid * Cn;
    float x0 = lg[lane];
    float x1 = (lane < Cn - 64) ? lg[64 + lane] : -3.4e38f;
    float mx = fmaxf(x0, x1);
    for (int m = 32; m; m >>= 1) mx = fmaxf(mx, __shfl_xor(mx, m, 64));
    float e0 = expf(x0 - mx);
    float e1 = (lane < Cn - 64) ? expf(x1 - mx) : 0.0f;
    float ssum = e0 + e1;
    for (int m = 32; m; m >>= 1) ssum += __shfl_xor(ssum, m, 64);

    const float4 pb = *reinterpret_cast<const float4*>(props + (size_t)wid * 4);
    float w = pb.z - pb.x, h = pb.w - pb.y;
    float cx = pb.x + 0.5f * w, cy = pb.y + 0.5f * h;
    const float* rrow = reg + (size_t)wid * (Cn * 4);

    u64 key0 = 0ull, key1 = 0ull;
    if (lane >= 1) {                     // class c = lane (1..63)
      float sc = e0 / ssum;
      if (sc > 0.05f) {
        float4 rv = *reinterpret_cast<const float4*>(rrow + lane * 4);
        float bx[4];
        decode_clip(rv, w, h, cx, cy, bx);
        if ((bx[2] - bx[0] >= 0.01f) && (bx[3] - bx[1] >= 0.01f)) {
          unsigned m = (unsigned)(p * CM1 + (lane - 1));
          key0 = ((u64)__float_as_uint(sc) << 32) | (0xFFFFFFFFu - m);
        }
      }
    }
    if (lane < Cn - 64) {                // class c = 64+lane (64..80)
      int c = 64 + lane;
      float sc = e1 / ssum;
      if (sc > 0.05f) {
        float4 rv = *reinterpret_cast<const float4*>(rrow + c * 4);
        float bx[4];
        decode_clip(rv, w, h, cx, cy, bx);
        if ((bx[2] - bx[0] >= 0.01f) && (bx[3] - bx[1] >= 0.01f)) {
          unsigned m = (unsigned)(p * CM1 + (c - 1));
          key1 = ((u64)__float_as_uint(sc) << 32) | (0xFFFFFFFFu - m);
        }
      }
    }
    u64 bal0 = __ballot(key0 != 0ull);
    u64 bal1 = __ballot(key1 != 0ull);
    int tot = __popcll(bal0) + __popcll(bal1);
    if (tot) {
      int base = 0;
      if (lane == 0) base = atomicAdd(&cnt_sh, tot);   // LDS atomic
      base = __shfl(base, 0, 64);
      int r0 = __popcll(bal0 & ((1ull << lane) - 1ull));
      int r1 = __popcll(bal0) + __popcll(bal1 & ((1ull << lane) - 1ull));
      if (key0) cbuf[base + r0] = key0;
      if (key1) cbuf[base + r1] = key1;
    }
  }
  __syncthreads();
  int n = cnt_sh;                         // <= 152
  for (int i = t; i < n; i += 256) slices[(size_t)blk * SSLOT + i] = cbuf[i];
  if (t == 0) scnt[blk] = n;
}

// ---------------- K2s: LDS hist -> T -> compact -> chunk-sort -> candA -------
__global__ __launch_bounds__(1024) void
k2s_select(const u64* __restrict__ slices, const int* __restrict__ scnt,
           u64* __restrict__ candA) {
  int b = blockIdx.x, t = threadIdx.x, lane = t & 63, wv = t >> 6;  // 16 waves
  __shared__ int histL[NBINS];     // 22.5 KB
  __shared__ u64 candL[CAP];       // 32 KB
  __shared__ int lcnt[NSEC2];      // 1 KB
  __shared__ int partial[256];
  __shared__ int sufAfter[256];
  __shared__ int tmax_sh, cnt_sh;

  // ---- zero hist, load section counts ----
  for (int i = t; i < NBINS; i += 1024) histL[i] = 0;
  if (t < NSEC2) lcnt[t] = scnt[b * NSEC2 + t];
  if (t == 0) { tmax_sh = 0; cnt_sh = 0; }
  __syncthreads();

  // ---- pass 1: histogram of all slice keys (LDS atomics) ----
  for (int sec = wv; sec < NSEC2; sec += 16) {
    int n = lcnt[sec];
    const u64* sl = slices + (size_t)(b * NSEC2 + sec) * SSLOT;
    for (int i = lane; i < n; i += 64)
      atomicAdd(&histL[score_bin((unsigned)(sl[i] >> 32))], 1);
  }
  __syncthreads();

  // ---- threshold T: max bin with suffix-count >= KPRE ----
  const int CH = NBINS / 256;  // 22
  if (t < 256) {
    int lo = t * CH, hi = lo + CH;
    int s = 0;
    for (int i = lo; i < hi; i++) s += histL[i];
    partial[t] = s;
  }
  __syncthreads();
  if (t < 256) sufAfter[t] = partial[t];
  __syncthreads();
  // reverse Hillis-Steele inclusive scan (suffix sums of partial)
  for (int s = 1; s < 256; s <<= 1) {
    int y = 0;
    if (t < 256 && t + s < 256) y = sufAfter[t + s];
    __syncthreads();
    if (t < 256) sufAfter[t] += y;
    __syncthreads();
  }
  if (t < 256) {
    int lo = t * CH, hi = lo + CH;
    int cum = (t + 1 < 256) ? sufAfter[t + 1] : 0;  // suffix AFTER this range
    int cand = -1;
    for (int i = hi - 1; i >= lo; i--) {
      cum += histL[i];
      if (cum >= KPRE) { cand = i; break; }
    }
    if (cand >= 0) atomicMax(&tmax_sh, cand);
  }
  // zero candL while threshold settles
  for (int i = t; i < CAP; i += 1024) candL[i] = 0ull;
  __syncthreads();
  int T = tmax_sh;

  // ---- pass 2: filter + compact into LDS ----
  for (int sec = wv; sec < NSEC2; sec += 16) {
    int n = lcnt[sec];
    const u64* sl = slices + (size_t)(b * NSEC2 + sec) * SSLOT;
    for (int i0 = 0; i0 < n; i0 += 64) {
      int i = i0 + lane;
      u64 key = (i < n) ? sl[i] : 0ull;
      bool pass = key && (score_bin((unsigned)(key >> 32)) >= T);
      u64 bal = __ballot(pass);
      int tot = __popcll(bal);
      if (tot) {
        int base = 0;
        if (lane == 0) base = atomicAdd(&cnt_sh, tot);
        base = __shfl(base, 0, 64);
        int rank = __popcll(bal & ((1ull << lane) - 1ull));
        int pos = base + rank;
        if (pass && pos < CAP) candL[pos] = key;
      }
    }
  }
  __syncthreads();

  // ---- in-LDS bitonic sort of each 512-chunk (desc) ----
  for (int k = 2; k <= 512; k <<= 1) {
    for (int j = k >> 1; j > 0; j >>= 1) {
      #pragma unroll
      for (int s = 0; s < 4; s++) {
        int i = t + s * 1024;
        int ixj = i ^ j;                 // j < 512 -> stays in chunk
        if (ixj > i) {
          u64 a = candL[i], c2 = candL[ixj];
          bool dir = (((i & 511) & k) == 0);  // chunk-local descending
          if ((a < c2) == dir) { candL[i] = c2; candL[ixj] = a; }
        }
      }
      __syncthreads();
    }
  }

  // ---- write sorted chunks ----
  #pragma unroll
  for (int s = 0; s < 4; s++) {
    int i = t + s * 1024;
    candA[(size_t)b * CAP + i] = candL[i];
  }
}

// in-place reg-staged merge-path round over LDS (desc, A-priority, exact)
template <int CHV>
__device__ __forceinline__ void mp_round(u64* buf, int base, int nA, int nB,
                                         int outLen, int tid) {
  const u64* A = buf + base;
  const u64* B = buf + base + nA;
  int d = tid * CHV;
  u64 rg[CHV];
  int cnt = 0;
  if (d < outLen) {
    int lo = max(0, d - nB), hi = min(d, nA);
    while (lo < hi) {
      int mid = (lo + hi) >> 1;
      if (A[mid] >= B[d - 1 - mid]) lo = mid + 1; else hi = mid;
    }
    int i = lo, j = d - lo;
    for (int e = 0; e < CHV && d + e < outLen; e++) {
      u64 v;
      if (j >= nB || (i < nA && A[i] >= B[j])) v = A[i++];
      else v = B[j++];
      rg[cnt++] = v;
    }
  }
  __syncthreads();
  for (int e = 0; e < cnt; e++) buf[base + d + e] = rg[e];
  __syncthreads();
}

// ---------------- K5: LDS merge tree + windowed bitmask NMS + output ---------
__global__ __launch_bounds__(1024) void
k5_merge_nms(u64* __restrict__ candA, const float* __restrict__ reg,
             const float* __restrict__ props, float* __restrict__ out) {
  int b = blockIdx.x, t = threadIdx.x, lane = t & 63, w = t >> 6;  // 16 waves
  __shared__ u64 bufA[CAP];            // 32 KB: keys (merge) then obox (NMS)
  __shared__ u64 maskb[256][4];        // 8 KB
  __shared__ u64 keepw[KPRE / 64];     // 256 B
  __shared__ int accI[NDET];
  __shared__ int kcnt_sh;
  float4* obox = (float4*)bufA;

  // ---- load 8 sorted 512-chunks ----
  #pragma unroll
  for (int s = 0; s < 4; s++) {
    int i = t + s * 1024;
    bufA[i] = candA[(size_t)b * CAP + i];
  }
  __syncthreads();
  // ---- merge rounds: 8x512 -> 4x1024 -> 2x2048 -> top-2048 ----
  mp_round<4>(bufA, (t >> 8) * 1024, 512, 512, 1024, t & 255);
  mp_round<4>(bufA, (t >> 9) * 2048, 1024, 1024, 2048, t & 511);
  mp_round<2>(bufA, 0, 2048, 2048, 2048, t);   // exact truncation

  // ---- spill merged keys to global, init keepw, decode obox (aliases) ----
  u64 k0 = bufA[t], k1 = bufA[t + 1024];
  candA[(size_t)b * CAP + t] = k0;
  candA[(size_t)b * CAP + t + 1024] = k1;
  {
    u64 bal = __ballot(k0 != 0ull);
    if (lane == 0) keepw[w] = bal;
    bal = __ballot(k1 != 0ull);
    if (lane == 0) keepw[16 + w] = bal;
  }
  __syncthreads();
  #pragma unroll
  for (int s = 0; s < 2; s++) {
    int j = t + s * 1024;
    u64 key = s ? k1 : k0;
    float bx[4]; int label; float sc;
    key_decode(key, b, reg, props, bx, label, sc);
    float off = (float)label * NMS_OFF;
    obox[j] = make_float4(bx[0] + off, bx[1] + off, bx[2] + off, bx[3] + off);
  }
  __syncthreads();

  // ---- windowed bitmask greedy NMS with early exit ----
  int kcount = 0;
  for (int w0 = 0; w0 < KPRE && kcount < NDET; w0 += 256) {
    // step1: suppress window cols by previously accepted boxes
    if (w0 > 0 && kcount > 0) {
      if (t < 256) {
        int j = w0 + t;
        u64 kwv = keepw[j >> 6];
        bool alive = (kwv >> (j & 63)) & 1ull;
        if (alive) {
          float4 jb = obox[j];
          float jar = fmaxf(jb.z - jb.x, 0.0f) * fmaxf(jb.w - jb.y, 0.0f);
          for (int a = 0; a < kcount; a++) {
            float4 ab = obox[accI[a]];
            float ix1 = fmaxf(ab.x, jb.x), iy1 = fmaxf(ab.y, jb.y);
            float ix2 = fminf(ab.z, jb.z), iy2 = fminf(ab.w, jb.w);
            float iw = fmaxf(ix2 - ix1, 0.0f), ih = fmaxf(iy2 - iy1, 0.0f);
            float inter = iw * ih;
            if (inter > 0.0f) {
              float aar = fmaxf(ab.z - ab.x, 0.0f) * fmaxf(ab.w - ab.y, 0.0f);
              float iou = inter / fmaxf(aar + jar - inter, 1e-9f);
              if (iou > 0.5f) { alive = false; break; }
            }
          }
        }
        u64 bal = __ballot(alive);
        if (lane == 0) keepw[(w0 >> 6) + (t >> 6)] = bal;
      }
      __syncthreads();
    }
    // step2: window-internal suppression bitmask (row r = t>>2, word wd = t&3)
    {
      int r = t >> 2, wd = t & 3;
      int rgp = w0 + r;
      bool ralive = (keepw[rgp >> 6] >> (rgp & 63)) & 1ull;
      float4 rb = obox[rgp];
      float rar = fmaxf(rb.z - rb.x, 0.0f) * fmaxf(rb.w - rb.y, 0.0f);
      u64 m = 0;
      if (ralive) {
        int cb0 = w0 + wd * 64;
        for (int jj = 0; jj < 64; jj++) {
          int cg = cb0 + jj;
          float4 cb = obox[cg];
          float ix1 = fmaxf(rb.x, cb.x), iy1 = fmaxf(rb.y, cb.y);
          float ix2 = fminf(rb.z, cb.z), iy2 = fminf(rb.w, cb.w);
          float iw = fmaxf(ix2 - ix1, 0.0f), ih = fmaxf(iy2 - iy1, 0.0f);
          float inter = iw * ih;
          if (inter > 0.0f && cg > rgp) {
            float car = fmaxf(cb.z - cb.x, 0.0f) * fmaxf(cb.w - cb.y, 0.0f);
            float iou = inter / fmaxf(rar + car - inter, 1e-9f);
            if (iou > 0.5f) m |= (1ull << jj);
          }
        }
      }
      maskb[r][wd] = m;
    }
    __syncthreads();
    // step3: single-wave serial greedy reduce over the window
    if (w == 0) {
      u64 kw0 = keepw[(w0 >> 6) + 0];
      u64 kw1 = keepw[(w0 >> 6) + 1];
      u64 kw2 = keepw[(w0 >> 6) + 2];
      u64 kw3 = keepw[(w0 >> 6) + 3];
      int kc = kcount;
      #pragma unroll
      for (int wq = 0; wq < 4; wq++) {
        u64 cw = (wq == 0) ? kw0 : (wq == 1) ? kw1 : (wq == 2) ? kw2 : kw3;
        if (cw == 0ull) continue;
        for (int rb0 = 0; rb0 < 64 && kc < NDET; rb0 += 4) {
          u64 gbits = (cw >> rb0) & 0xFull;
          int r = wq * 64 + rb0;
          u64 rm0a = maskb[r][0],   rm0b = maskb[r][1],   rm0c = maskb[r][2],   rm0d = maskb[r][3];
          u64 rm1a = maskb[r+1][0], rm1b = maskb[r+1][1], rm1c = maskb[r+1][2], rm1d = maskb[r+1][3];
          u64 rm2a = maskb[r+2][0], rm2b = maskb[r+2][1], rm2c = maskb[r+2][2], rm2d = maskb[r+2][3];
          u64 rm3a = maskb[r+3][0], rm3b = maskb[r+3][1], rm3c = maskb[r+3][2], rm3d = maskb[r+3][3];
          if (gbits == 0ull) continue;
          #pragma unroll
          for (int d = 0; d < 4; d++) {
            u64 cwq = (wq == 0) ? kw0 : (wq == 1) ? kw1 : (wq == 2) ? kw2 : kw3;
            if ((cwq >> (rb0 + d)) & 1ull) {
              if (lane == 0) accI[kc] = w0 + r + d;
              kc++;
              if (kc >= NDET) break;
              u64 ma = (d == 0) ? rm0a : (d == 1) ? rm1a : (d == 2) ? rm2a : rm3a;
              u64 mb = (d == 0) ? rm0b : (d == 1) ? rm1b : (d == 2) ? rm2b : rm3b;
              u64 mc = (d == 0) ? rm0c : (d == 1) ? rm1c : (d == 2) ? rm2c : rm3c;
              u64 md = (d == 0) ? rm0d : (d == 1) ? rm1d : (d == 2) ? rm2d : rm3d;
              kw0 &= ~ma; kw1 &= ~mb; kw2 &= ~mc; kw3 &= ~md;
            }
          }
          cw = (wq == 0) ? kw0 : (wq == 1) ? kw1 : (wq == 2) ? kw2 : kw3;
        }
      }
      if (lane == 0) {
        keepw[(w0 >> 6) + 0] = kw0;
        keepw[(w0 >> 6) + 1] = kw1;
        keepw[(w0 >> 6) + 2] = kw2;
        keepw[(w0 >> 6) + 3] = kw3;
        kcnt_sh = kc;
      }
    }
    __syncthreads();
    kcount = kcnt_sh;
  }

  // rare path: fewer than 100 kept -> backfill non-kept ascending
  if (t == 0 && kcount < NDET) {
    int run = kcount;
    for (int wq = 0; wq < KPRE / 64 && run < NDET; wq++) {
      u64 nk = ~keepw[wq];
      while (nk && run < NDET) {
        int bit2 = __ffsll((long long)nk) - 1;
        nk &= nk - 1;
        accI[run++] = wq * 64 + bit2;
      }
    }
  }
  __syncthreads();

  if (t < NDET) {
    int k = accI[t];
    bool kept = t < kcount;
    u64 key = candA[(size_t)b * CAP + k];    // merged keys spilled above
    float bx[4]; int label; float sc;
    key_decode(key, b, reg, props, bx, label, sc);
    int oi = b * NDET + t;
    out[(size_t)oi * 4 + 0] = bx[0];
    out[(size_t)oi * 4 + 1] = bx[1];
    out[(size_t)oi * 4 + 2] = bx[2];
    out[(size_t)oi * 4 + 3] = bx[3];
    out[Bn * NDET * 4 + oi] = kept ? sc : -1.0f;
    out[Bn * NDET * 5 + oi] = (float)label;
    out[Bn * NDET * 6 + oi] = kept ? 1.0f : 0.0f;
  }
}

extern "C" void kernel_launch(void* const* d_in, const int* in_sizes, int n_in,
                              void* d_out, int out_size, void* d_ws, size_t ws_size,
                              hipStream_t stream) {
  const float* logits = (const float*)d_in[0];
  const float* reg    = (const float*)d_in[1];
  const float* props  = (const float*)d_in[2];
  float* out = (float*)d_out;
  char* ws = (char*)d_ws;

  u64* slices = (u64*)(ws + OFF_SL);
  int* scnt   = (int*)(ws + OFF_SC);
  u64* candA  = (u64*)(ws + OFF_CANDA);

  k1_score<<<Bn * NSEC2, 256, 0, stream>>>(logits, reg, props, slices, scnt);
  k2s_select<<<Bn, 1024, 0, stream>>>(slices, scnt, candA);
  k5_merge_nms<<<Bn, 1024, 0, stream>>>(candA, reg, props, out);
}

// Round 10
// 138.056 us; speedup vs baseline: 1.1044x; 1.1044x over previous
//
#include <hip/hip_runtime.h>
#include <cstdint>
#include <cstddef>

typedef unsigned long long u64;

// ---------------- problem constants ----------------
constexpr int Bn   = 8;
constexpr int Pn   = 2000;
constexpr int Cn   = 81;
constexpr int CM1  = 80;
constexpr int KPRE = 2048;
constexpr int NDET = 100;
constexpr int SECP = 8;              // proposals per K1 block
constexpr int NSEC2 = Pn / SECP;     // 250 sections per image
constexpr int SSLOT = 160;           // slice stride (hard max 8*19 = 152)
constexpr int CAP  = 4096;           // post-threshold cap
constexpr int NBINS = 5632;          // score-bits histogram bins
constexpr int BINOFF = (122 << 10);  // exponent 122 (scores > 0.05 > 2^-5)
constexpr float W_IMG = 1333.0f;
constexpr float H_IMG = 800.0f;
constexpr float XFORM_CLIP = 4.135166556742356f; // log(1000/16)
constexpr float NMS_OFF = 1334.0f;               // max(W,H)+1

// ---------------- ws layout (bytes) ----------------
constexpr size_t OFF_HIST = 0;                                    // memset to 0
constexpr size_t ZERO_BYTES = (size_t)Bn * NBINS * 4;             // 180224
constexpr size_t OFF_SL   = ZERO_BYTES;                           // Bn*NSEC2*SSLOT u64
constexpr size_t OFF_SC   = OFF_SL + (size_t)Bn * NSEC2 * SSLOT * 8; // Bn*NSEC2 int
constexpr size_t OFF_CANDA = OFF_SC + (size_t)Bn * NSEC2 * 4;     // Bn*CAP u64

__device__ __forceinline__ void decode_clip(const float4 rv, float w, float h,
                                            float cx, float cy, float out[4]) {
  float dx = rv.x / 10.0f;
  float dy = rv.y / 10.0f;
  float dw = fminf(rv.z / 5.0f, XFORM_CLIP);
  float dh = fminf(rv.w / 5.0f, XFORM_CLIP);
  float pcx = dx * w + cx;
  float pcy = dy * h + cy;
  float pw = expf(dw) * w;
  float ph = expf(dh) * h;
  out[0] = fminf(fmaxf(pcx - 0.5f * pw, 0.0f), W_IMG);
  out[1] = fminf(fmaxf(pcy - 0.5f * ph, 0.0f), H_IMG);
  out[2] = fminf(fmaxf(pcx + 0.5f * pw, 0.0f), W_IMG);
  out[3] = fminf(fmaxf(pcy + 0.5f * ph, 0.0f), H_IMG);
}

__device__ __forceinline__ int score_bin(unsigned bits) {
  int bin = (int)(bits >> 13) - BINOFF;
  return min(max(bin, 0), NBINS - 1);
}

// decode a candidate key into raw clipped box + label + score
__device__ __forceinline__ void key_decode(u64 key, int b,
                                           const float* __restrict__ reg,
                                           const float* __restrict__ props,
                                           float bx[4], int& label, float& sc) {
  sc = __uint_as_float((unsigned)(key >> 32));
  bx[0] = bx[1] = bx[2] = bx[3] = 0.0f;
  label = 0;
  if (key != 0ull) {
    int m = (int)(0xFFFFFFFFu - (unsigned)key);
    int p = m / CM1;
    int c = m - p * CM1 + 1;
    int nidx = b * Pn + p;
    const float4 pb = *reinterpret_cast<const float4*>(props + (size_t)nidx * 4);
    float w = pb.z - pb.x, h = pb.w - pb.y;
    float cx = pb.x + 0.5f * w, cy = pb.y + 0.5f * h;
    float4 rv = *reinterpret_cast<const float4*>(reg + (size_t)nidx * (Cn * 4) + c * 4);
    decode_clip(rv, w, h, cx, cy, bx);
    label = c;
  }
}

// ---------------- K1: softmax + decode + valid -> slices + histogram ---------
__global__ __launch_bounds__(256) void
k1_score(const float* __restrict__ logits, const float* __restrict__ reg,
         const float* __restrict__ props, u64* __restrict__ slices,
         int* __restrict__ scnt, int* __restrict__ hist) {
  int blk = blockIdx.x, t = threadIdx.x, lane = t & 63, wv = t >> 6;
  int b = blk / NSEC2, sec = blk % NSEC2;
  __shared__ u64 cbuf[SSLOT];
  __shared__ int cnt_sh;
  if (t == 0) cnt_sh = 0;
  __syncthreads();
  int* hrow = hist + (size_t)b * NBINS;

  #pragma unroll
  for (int pp = wv; pp < SECP; pp += 4) {
    int p = sec * SECP + pp;
    int wid = b * Pn + p;
    const float* lg = logits + (size_t)wid * Cn;
    float x0 = lg[lane];
    float x1 = (lane < Cn - 64) ? lg[64 + lane] : -3.4e38f;
    float mx = fmaxf(x0, x1);
    for (int m = 32; m; m >>= 1) mx = fmaxf(mx, __shfl_xor(mx, m, 64));
    float e0 = expf(x0 - mx);
    float e1 = (lane < Cn - 64) ? expf(x1 - mx) : 0.0f;
    float ssum = e0 + e1;
    for (int m = 32; m; m >>= 1) ssum += __shfl_xor(ssum, m, 64);

    const float4 pb = *reinterpret_cast<const float4*>(props + (size_t)wid * 4);
    float w = pb.z - pb.x, h = pb.w - pb.y;
    float cx = pb.x + 0.5f * w, cy = pb.y + 0.5f * h;
    const float* rrow = reg + (size_t)wid * (Cn * 4);

    u64 key0 = 0ull, key1 = 0ull;
    if (lane >= 1) {                     // class c = lane (1..63)
      float sc = e0 / ssum;
      if (sc > 0.05f) {
        float4 rv = *reinterpret_cast<const float4*>(rrow + lane * 4);
        float bx[4];
        decode_clip(rv, w, h, cx, cy, bx);
        if ((bx[2] - bx[0] >= 0.01f) && (bx[3] - bx[1] >= 0.01f)) {
          unsigned m = (unsigned)(p * CM1 + (lane - 1));
          key0 = ((u64)__float_as_uint(sc) << 32) | (0xFFFFFFFFu - m);
        }
      }
    }
    if (lane < Cn - 64) {                // class c = 64+lane (64..80)
      int c = 64 + lane;
      float sc = e1 / ssum;
      if (sc > 0.05f) {
        float4 rv = *reinterpret_cast<const float4*>(rrow + c * 4);
        float bx[4];
        decode_clip(rv, w, h, cx, cy, bx);
        if ((bx[2] - bx[0] >= 0.01f) && (bx[3] - bx[1] >= 0.01f)) {
          unsigned m = (unsigned)(p * CM1 + (c - 1));
          key1 = ((u64)__float_as_uint(sc) << 32) | (0xFFFFFFFFu - m);
        }
      }
    }
    u64 bal0 = __ballot(key0 != 0ull);
    u64 bal1 = __ballot(key1 != 0ull);
    int tot = __popcll(bal0) + __popcll(bal1);
    if (tot) {
      int base = 0;
      if (lane == 0) base = atomicAdd(&cnt_sh, tot);   // LDS atomic
      base = __shfl(base, 0, 64);
      int r0 = __popcll(bal0 & ((1ull << lane) - 1ull));
      int r1 = __popcll(bal0) + __popcll(bal1 & ((1ull << lane) - 1ull));
      if (key0) {
        cbuf[base + r0] = key0;
        atomicAdd(&hrow[score_bin((unsigned)(key0 >> 32))], 1);
      }
      if (key1) {
        cbuf[base + r1] = key1;
        atomicAdd(&hrow[score_bin((unsigned)(key1 >> 32))], 1);
      }
    }
  }
  __syncthreads();
  int n = cnt_sh;                         // <= 152
  for (int i = t; i < n; i += 256) slices[(size_t)blk * SSLOT + i] = cbuf[i];
  if (t == 0) scnt[blk] = n;
}

// ---------------- K2c: threshold T + filter + compact -> candA --------------
__global__ __launch_bounds__(1024) void
k2c_compact(const int* __restrict__ hist, const u64* __restrict__ slices,
            const int* __restrict__ scnt, u64* __restrict__ candA) {
  int b = blockIdx.x, t = threadIdx.x, lane = t & 63, wv = t >> 6;  // 16 waves
  __shared__ int partial[256];
  __shared__ int sufAfter[256];
  __shared__ int lcnt[NSEC2];
  __shared__ int tmax_sh, cnt_sh;
  const int CH = NBINS / 256;  // 22
  const int* hrow = hist + (size_t)b * NBINS;

  if (t == 0) { tmax_sh = 0; cnt_sh = 0; }
  if (t < 256) {
    int lo = t * CH, hi = lo + CH;
    int s = 0;
    for (int i = lo; i < hi; i++) s += hrow[i];
    partial[t] = s;
  }
  if (t < NSEC2) lcnt[t] = scnt[b * NSEC2 + t];
  __syncthreads();
  if (t < 256) sufAfter[t] = partial[t];
  __syncthreads();
  // parallel reverse Hillis-Steele: sufAfter[t] = sum_{q>=t} partial[q]
  for (int s = 1; s < 256; s <<= 1) {
    int y = 0;
    if (t < 256 && t + s < 256) y = sufAfter[t + s];
    __syncthreads();
    if (t < 256) sufAfter[t] += y;
    __syncthreads();
  }
  if (t < 256) {
    int lo = t * CH, hi = lo + CH;
    int cum = (t + 1 < 256) ? sufAfter[t + 1] : 0;  // suffix AFTER this range
    int cand = -1;
    for (int i = hi - 1; i >= lo; i--) {
      cum += hrow[i];
      if (cum >= KPRE) { cand = i; break; }
    }
    if (cand >= 0) atomicMax(&tmax_sh, cand);
  }
  __syncthreads();
  int T = tmax_sh;

  // wave wv handles sections wv, wv+16, ... ; coalesced 64-wide slice reads
  for (int sec = wv; sec < NSEC2; sec += 16) {
    int n = lcnt[sec];
    const u64* sl = slices + (size_t)(b * NSEC2 + sec) * SSLOT;
    for (int i0 = 0; i0 < n; i0 += 64) {
      int i = i0 + lane;
      u64 key = (i < n) ? sl[i] : 0ull;
      bool pass = key && (score_bin((unsigned)(key >> 32)) >= T);
      u64 bal = __ballot(pass);
      int tot = __popcll(bal);
      if (tot) {
        int base = 0;
        if (lane == 0) base = atomicAdd(&cnt_sh, tot);
        base = __shfl(base, 0, 64);
        int rank = __popcll(bal & ((1ull << lane) - 1ull));
        int pos = base + rank;
        if (pass && pos < CAP) candA[(size_t)b * CAP + pos] = key;
      }
    }
  }
  __syncthreads();
  for (int i = min(cnt_sh, CAP) + t; i < CAP; i += 1024)
    candA[(size_t)b * CAP + i] = 0ull;
}

// ---------------- K4a: per-512-chunk bitonic sort (desc) --------------------
__global__ __launch_bounds__(256) void
k4a_chunk(u64* __restrict__ candA) {
  __shared__ u64 sk[512];  // 4 KB
  int blk = blockIdx.x, t = threadIdx.x;
  int b = blk >> 3, ch = blk & 7;
  int base = ch * 512;
  #pragma unroll
  for (int i = t; i < 512; i += 256) sk[i] = candA[(size_t)b * CAP + base + i];
  __syncthreads();
  for (int k = 2; k <= 512; k <<= 1) {
    for (int j = k >> 1; j > 0; j >>= 1) {
      #pragma unroll
      for (int i = t; i < 512; i += 256) {
        int ixj = i ^ j;
        if (ixj > i) {
          u64 a = sk[i], c2 = sk[ixj];
          bool dir = ((i & k) == 0);  // descending overall
          if ((a < c2) == dir) { sk[i] = c2; sk[ixj] = a; }
        }
      }
      __syncthreads();
    }
  }
  #pragma unroll
  for (int i = t; i < 512; i += 256)
    candA[(size_t)b * CAP + base + i] = sk[i];
}

// in-place reg-staged merge-path round over LDS (desc, A-priority, exact)
template <int CHV>
__device__ __forceinline__ void mp_round(u64* buf, int base, int nA, int nB,
                                         int outLen, int tid) {
  const u64* A = buf + base;
  const u64* B = buf + base + nA;
  int d = tid * CHV;
  u64 rg[CHV];
  int cnt = 0;
  if (d < outLen) {
    int lo = max(0, d - nB), hi = min(d, nA);
    while (lo < hi) {
      int mid = (lo + hi) >> 1;
      if (A[mid] >= B[d - 1 - mid]) lo = mid + 1; else hi = mid;
    }
    int i = lo, j = d - lo;
    for (int e = 0; e < CHV && d + e < outLen; e++) {
      u64 v;
      if (j >= nB || (i < nA && A[i] >= B[j])) v = A[i++];
      else v = B[j++];
      rg[cnt++] = v;
    }
  }
  __syncthreads();
  for (int e = 0; e < cnt; e++) buf[base + d + e] = rg[e];
  __syncthreads();
}

// ---------------- K5: LDS merge tree + windowed bitmask NMS + output ---------
__global__ __launch_bounds__(1024) void
k5_merge_nms(u64* __restrict__ candA, const float* __restrict__ reg,
             const float* __restrict__ props, float* __restrict__ out) {
  int b = blockIdx.x, t = threadIdx.x, lane = t & 63, w = t >> 6;  // 16 waves
  __shared__ u64 bufA[CAP];            // 32 KB: keys (merge) then obox (NMS)
  __shared__ u64 maskb[256][4];        // 8 KB
  __shared__ u64 keepw[KPRE / 64];     // 256 B
  __shared__ int accI[NDET];
  __shared__ int kcnt_sh;
  float4* obox = (float4*)bufA;

  // ---- load 8 sorted 512-chunks ----
  #pragma unroll
  for (int s = 0; s < 4; s++) {
    int i = t + s * 1024;
    bufA[i] = candA[(size_t)b * CAP + i];
  }
  __syncthreads();
  // ---- merge rounds: 8x512 -> 4x1024 -> 2x2048 -> top-2048 ----
  mp_round<4>(bufA, (t >> 8) * 1024, 512, 512, 1024, t & 255);
  mp_round<4>(bufA, (t >> 9) * 2048, 1024, 1024, 2048, t & 511);
  mp_round<2>(bufA, 0, 2048, 2048, 2048, t);   // exact truncation

  // ---- spill merged keys to global, init keepw, decode obox (aliases) ----
  u64 k0 = bufA[t], k1 = bufA[t + 1024];
  candA[(size_t)b * CAP + t] = k0;
  candA[(size_t)b * CAP + t + 1024] = k1;
  {
    u64 bal = __ballot(k0 != 0ull);
    if (lane == 0) keepw[w] = bal;
    bal = __ballot(k1 != 0ull);
    if (lane == 0) keepw[16 + w] = bal;
  }
  __syncthreads();
  #pragma unroll
  for (int s = 0; s < 2; s++) {
    int j = t + s * 1024;
    u64 key = s ? k1 : k0;
    float bx[4]; int label; float sc;
    key_decode(key, b, reg, props, bx, label, sc);
    float off = (float)label * NMS_OFF;
    obox[j] = make_float4(bx[0] + off, bx[1] + off, bx[2] + off, bx[3] + off);
  }
  __syncthreads();

  // ---- windowed bitmask greedy NMS with early exit ----
  int kcount = 0;
  for (int w0 = 0; w0 < KPRE && kcount < NDET; w0 += 256) {
    // step1: suppress window cols by previously accepted boxes
    if (w0 > 0 && kcount > 0) {
      if (t < 256) {
        int j = w0 + t;
        u64 kwv = keepw[j >> 6];
        bool alive = (kwv >> (j & 63)) & 1ull;
        if (alive) {
          float4 jb = obox[j];
          float jar = fmaxf(jb.z - jb.x, 0.0f) * fmaxf(jb.w - jb.y, 0.0f);
          for (int a = 0; a < kcount; a++) {
            float4 ab = obox[accI[a]];
            float ix1 = fmaxf(ab.x, jb.x), iy1 = fmaxf(ab.y, jb.y);
            float ix2 = fminf(ab.z, jb.z), iy2 = fminf(ab.w, jb.w);
            float iw = fmaxf(ix2 - ix1, 0.0f), ih = fmaxf(iy2 - iy1, 0.0f);
            float inter = iw * ih;
            if (inter > 0.0f) {
              float aar = fmaxf(ab.z - ab.x, 0.0f) * fmaxf(ab.w - ab.y, 0.0f);
              float iou = inter / fmaxf(aar + jar - inter, 1e-9f);
              if (iou > 0.5f) { alive = false; break; }
            }
          }
        }
        u64 bal = __ballot(alive);
        if (lane == 0) keepw[(w0 >> 6) + (t >> 6)] = bal;
      }
      __syncthreads();
    }
    // step2: window-internal suppression bitmask (row r = t>>2, word wd = t&3)
    {
      int r = t >> 2, wd = t & 3;
      int rgp = w0 + r;
      bool ralive = (keepw[rgp >> 6] >> (rgp & 63)) & 1ull;
      float4 rb = obox[rgp];
      float rar = fmaxf(rb.z - rb.x, 0.0f) * fmaxf(rb.w - rb.y, 0.0f);
      u64 m = 0;
      if (ralive) {
        int cb0 = w0 + wd * 64;
        for (int jj = 0; jj < 64; jj++) {
          int cg = cb0 + jj;
          float4 cb = obox[cg];
          float ix1 = fmaxf(rb.x, cb.x), iy1 = fmaxf(rb.y, cb.y);
          float ix2 = fminf(rb.z, cb.z), iy2 = fminf(rb.w, cb.w);
          float iw = fmaxf(ix2 - ix1, 0.0f), ih = fmaxf(iy2 - iy1, 0.0f);
          float inter = iw * ih;
          if (inter > 0.0f && cg > rgp) {
            float car = fmaxf(cb.z - cb.x, 0.0f) * fmaxf(cb.w - cb.y, 0.0f);
            float iou = inter / fmaxf(rar + car - inter, 1e-9f);
            if (iou > 0.5f) m |= (1ull << jj);
          }
        }
      }
      maskb[r][wd] = m;
    }
    __syncthreads();
    // step3: single-wave serial greedy reduce over the window
    if (w == 0) {
      u64 kw0 = keepw[(w0 >> 6) + 0];
      u64 kw1 = keepw[(w0 >> 6) + 1];
      u64 kw2 = keepw[(w0 >> 6) + 2];
      u64 kw3 = keepw[(w0 >> 6) + 3];
      int kc = kcount;
      #pragma unroll
      for (int wq = 0; wq < 4; wq++) {
        u64 cw = (wq == 0) ? kw0 : (wq == 1) ? kw1 : (wq == 2) ? kw2 : kw3;
        if (cw == 0ull) continue;
        for (int rb0 = 0; rb0 < 64 && kc < NDET; rb0 += 4) {
          u64 gbits = (cw >> rb0) & 0xFull;
          int r = wq * 64 + rb0;
          u64 rm0a = maskb[r][0],   rm0b = maskb[r][1],   rm0c = maskb[r][2],   rm0d = maskb[r][3];
          u64 rm1a = maskb[r+1][0], rm1b = maskb[r+1][1], rm1c = maskb[r+1][2], rm1d = maskb[r+1][3];
          u64 rm2a = maskb[r+2][0], rm2b = maskb[r+2][1], rm2c = maskb[r+2][2], rm2d = maskb[r+2][3];
          u64 rm3a = maskb[r+3][0], rm3b = maskb[r+3][1], rm3c = maskb[r+3][2], rm3d = maskb[r+3][3];
          if (gbits == 0ull) continue;
          #pragma unroll
          for (int d = 0; d < 4; d++) {
            u64 cwq = (wq == 0) ? kw0 : (wq == 1) ? kw1 : (wq == 2) ? kw2 : kw3;
            if ((cwq >> (rb0 + d)) & 1ull) {
              if (lane == 0) accI[kc] = w0 + r + d;
              kc++;
              if (kc >= NDET) break;
              u64 ma = (d == 0) ? rm0a : (d == 1) ? rm1a : (d == 2) ? rm2a : rm3a;
              u64 mb = (d == 0) ? rm0b : (d == 1) ? rm1b : (d == 2) ? rm2b : rm3b;
              u64 mc = (d == 0) ? rm0c : (d == 1) ? rm1c : (d == 2) ? rm2c : rm3c;
              u64 md = (d == 0) ? rm0d : (d == 1) ? rm1d : (d == 2) ? rm2d : rm3d;
              kw0 &= ~ma; kw1 &= ~mb; kw2 &= ~mc; kw3 &= ~md;
            }
          }
          cw = (wq == 0) ? kw0 : (wq == 1) ? kw1 : (wq == 2) ? kw2 : kw3;
        }
      }
      if (lane == 0) {
        keepw[(w0 >> 6) + 0] = kw0;
        keepw[(w0 >> 6) + 1] = kw1;
        keepw[(w0 >> 6) + 2] = kw2;
        keepw[(w0 >> 6) + 3] = kw3;
        kcnt_sh = kc;
      }
    }
    __syncthreads();
    kcount = kcnt_sh;
  }

  // rare path: fewer than 100 kept -> backfill non-kept ascending
  if (t == 0 && kcount < NDET) {
    int run = kcount;
    for (int wq = 0; wq < KPRE / 64 && run < NDET; wq++) {
      u64 nk = ~keepw[wq];
      while (nk && run < NDET) {
        int bit2 = __ffsll((long long)nk) - 1;
        nk &= nk - 1;
        accI[run++] = wq * 64 + bit2;
      }
    }
  }
  __syncthreads();

  if (t < NDET) {
    int k = accI[t];
    bool kept = t < kcount;
    u64 key = candA[(size_t)b * CAP + k];    // merged keys spilled above
    float bx[4]; int label; float sc;
    key_decode(key, b, reg, props, bx, label, sc);
    int oi = b * NDET + t;
    out[(size_t)oi * 4 + 0] = bx[0];
    out[(size_t)oi * 4 + 1] = bx[1];
    out[(size_t)oi * 4 + 2] = bx[2];
    out[(size_t)oi * 4 + 3] = bx[3];
    out[Bn * NDET * 4 + oi] = kept ? sc : -1.0f;
    out[Bn * NDET * 5 + oi] = (float)label;
    out[Bn * NDET * 6 + oi] = kept ? 1.0f : 0.0f;
  }
}

extern "C" void kernel_launch(void* const* d_in, const int* in_sizes, int n_in,
                              void* d_out, int out_size, void* d_ws, size_t ws_size,
                              hipStream_t stream) {
  const float* logits = (const float*)d_in[0];
  const float* reg    = (const float*)d_in[1];
  const float* props  = (const float*)d_in[2];
  float* out = (float*)d_out;
  char* ws = (char*)d_ws;

  int* hist   = (int*)(ws + OFF_HIST);
  u64* slices = (u64*)(ws + OFF_SL);
  int* scnt   = (int*)(ws + OFF_SC);
  u64* candA  = (u64*)(ws + OFF_CANDA);

  hipMemsetAsync(ws + OFF_HIST, 0, ZERO_BYTES, stream);
  k1_score<<<Bn * NSEC2, 256, 0, stream>>>(logits, reg, props, slices, scnt, hist);
  k2c_compact<<<Bn, 1024, 0, stream>>>(hist, slices, scnt, candA);
  k4a_chunk<<<Bn * 8, 256, 0, stream>>>(candA);
  k5_merge_nms<<<Bn, 1024, 0, stream>>>(candA, reg, props, out);
}